// Round 1
// baseline (322.198 us; speedup 1.0000x reference)
//
#include <hip/hip_runtime.h>
#include <stdint.h>

#define B_   128
#define N_   512
#define FIN  128
#define FOUT 64

using bf16x8 = __attribute__((ext_vector_type(8))) short;
using f32x4  = __attribute__((ext_vector_type(4))) float;

__device__ inline unsigned short f2bf(float x) {
    union { float f; uint32_t u; } c; c.f = x;
    uint32_t u = c.u;
    return (unsigned short)((u + 0x7FFFu + ((u >> 16) & 1u)) >> 16);  // RNE
}

// ---------------- kernel 0: transpose W (128x64 -> 64x128) ----------------
__global__ void k_wt(const float* __restrict__ W, float* __restrict__ Wt) {
    for (int i = threadIdx.x; i < FIN * FOUT; i += 256) {
        int k = i >> 6, f = i & 63;
        Wt[f * FIN + k] = W[i];
    }
}

// ---------------- kernel 1: h = X @ W (fp32), ht[b][f][j], s, t ----------------
// lane = one row of X held in VGPRs; Wt row is wave-uniform -> s_load + v_fmac.
__global__ __launch_bounds__(256) void k_h(const float* __restrict__ X,
                                           const float* __restrict__ Wt,
                                           const float* __restrict__ a,
                                           float* __restrict__ ht,
                                           float* __restrict__ s,
                                           float* __restrict__ t) {
    int row = blockIdx.x * 256 + threadIdx.x;   // 0..65535 = b*512 + j
    int b = row >> 9, j = row & (N_ - 1);
    const float* xp = X + (size_t)row * FIN;

    float x[FIN];
#pragma unroll
    for (int k = 0; k < FIN; k += 4) {
        float4 v = *(const float4*)(xp + k);
        x[k] = v.x; x[k + 1] = v.y; x[k + 2] = v.z; x[k + 3] = v.w;
    }

    float sa = 0.f, ta = 0.f;
    for (int f = 0; f < FOUT; ++f) {
        const float* wr = Wt + f * FIN;        // uniform address -> scalar loads
        float acc = 0.f;
#pragma unroll
        for (int k = 0; k < FIN; ++k) acc += x[k] * wr[k];
        ht[((size_t)(b * FOUT + f)) * N_ + j] = acc;   // coalesced over lanes (j)
        sa += acc * a[f];
        ta += acc * a[FOUT + f];
    }
    s[row] = sa;
    t[row] = ta;
}

// ---------------- kernel 2: attention + aggregation (bf16 MFMA) ----------------
// block = half batch (256 rows). H[b] staged in LDS as pre-swizzled B-fragments.
// P generated in A-fragment layout; softmax without max-subtraction; normalize
// in the epilogue by the fp32 row-sum l.
__global__ __launch_bounds__(256) void k_attn(const int*   __restrict__ adj,
                                              const float* __restrict__ ht,
                                              const float* __restrict__ s,
                                              const float* __restrict__ t,
                                              float*       __restrict__ out) {
    __shared__ bf16x8 hstage[64 * 64];   // [ks*4+nt][lane] -> 64 KB

    const int b  = blockIdx.x >> 1;
    const int i0 = (blockIdx.x & 1) * 256;
    const int tid  = threadIdx.x;
    const int w    = tid >> 6;
    const int lane = tid & 63;
    const int q    = lane >> 4;       // 0..3
    const int m    = lane & 15;       // 0..15

    // ---- stage H[b] (fp32 -> bf16 fragments) ----
    const float* hb = ht + (size_t)b * FOUT * N_;
    for (int pp = 0; pp < 16; ++pp) {
        int pi = w * 16 + pp;          // = ks*4 + nt
        int ks = pi >> 2, nt = pi & 3;
        const float* src = hb + (size_t)(nt * 16 + m) * N_ + ks * 32 + q * 8;
        float4 v0 = *(const float4*)src;
        float4 v1 = *(const float4*)(src + 4);
        bf16x8 fr;
        fr[0] = (short)f2bf(v0.x); fr[1] = (short)f2bf(v0.y);
        fr[2] = (short)f2bf(v0.z); fr[3] = (short)f2bf(v0.w);
        fr[4] = (short)f2bf(v1.x); fr[5] = (short)f2bf(v1.y);
        fr[6] = (short)f2bf(v1.z); fr[7] = (short)f2bf(v1.w);
        hstage[pi * 64 + lane] = fr;   // lane-contiguous b128: conflict-free
    }
    __syncthreads();

    const float* tb = t + b * N_;
    const float* sb = s + b * N_ + i0;

    for (int rt = w; rt < 16; rt += 4) {            // 4 row-tiles per wave
        const int irow = i0 + rt * 16 + m;          // this lane's A row
        const float s_i = sb[rt * 16 + m];
        const int* adjrow = adj + ((size_t)(b * N_) + irow) * N_;

        f32x4 acc0 = {0.f, 0.f, 0.f, 0.f};
        f32x4 acc1 = {0.f, 0.f, 0.f, 0.f};
        f32x4 acc2 = {0.f, 0.f, 0.f, 0.f};
        f32x4 acc3 = {0.f, 0.f, 0.f, 0.f};
        float lsum = 0.f;

        for (int ks = 0; ks < 16; ++ks) {
            const int jb = ks * 32 + q * 8;
            float4 t0 = *(const float4*)(tb + jb);
            float4 t1 = *(const float4*)(tb + jb + 4);
            int4  a0 = *(const int4*)(adjrow + jb);
            int4  a1 = *(const int4*)(adjrow + jb + 4);

            float tj[8] = {t0.x, t0.y, t0.z, t0.w, t1.x, t1.y, t1.z, t1.w};
            int   av[8] = {a0.x, a0.y, a0.z, a0.w, a1.x, a1.y, a1.z, a1.w};
            float pv[8];
#pragma unroll
            for (int u = 0; u < 8; ++u) {
                float e = s_i + tj[u];
                e = fmaxf(e, 0.2f * e);             // leaky_relu(e, 0.2)
                pv[u] = (av[u] > 0) ? __expf(e) : 0.0f;
                lsum += pv[u];
            }
            bf16x8 af;
#pragma unroll
            for (int u = 0; u < 8; ++u) af[u] = (short)f2bf(pv[u]);

            bf16x8 b0 = hstage[(ks * 4 + 0) * 64 + lane];
            bf16x8 b1 = hstage[(ks * 4 + 1) * 64 + lane];
            bf16x8 b2 = hstage[(ks * 4 + 2) * 64 + lane];
            bf16x8 b3 = hstage[(ks * 4 + 3) * 64 + lane];

            acc0 = __builtin_amdgcn_mfma_f32_16x16x32_bf16(af, b0, acc0, 0, 0, 0);
            acc1 = __builtin_amdgcn_mfma_f32_16x16x32_bf16(af, b1, acc1, 0, 0, 0);
            acc2 = __builtin_amdgcn_mfma_f32_16x16x32_bf16(af, b2, acc2, 0, 0, 0);
            acc3 = __builtin_amdgcn_mfma_f32_16x16x32_bf16(af, b3, acc3, 0, 0, 0);
        }

        // row-sum l: reduce over q (lanes differ in bits 4,5)
        lsum += __shfl_xor(lsum, 16, 64);
        lsum += __shfl_xor(lsum, 32, 64);
        // now lane (q,m) holds l[row m of this tile]

#pragma unroll
        for (int reg = 0; reg < 4; ++reg) {
            // C/D layout: col = lane&15 (feature), row = q*4 + reg
            float lr = __shfl(lsum, q * 4 + reg, 64);   // l for C-row q*4+reg
            float inv = 1.0f / lr;
            int orow = i0 + rt * 16 + q * 4 + reg;
            size_t obase = ((size_t)(b * N_) + orow) * FOUT + m;
            float v0 = acc0[reg] * inv; v0 = fmaxf(v0, 0.01f * v0);
            float v1 = acc1[reg] * inv; v1 = fmaxf(v1, 0.01f * v1);
            float v2 = acc2[reg] * inv; v2 = fmaxf(v2, 0.01f * v2);
            float v3 = acc3[reg] * inv; v3 = fmaxf(v3, 0.01f * v3);
            out[obase +  0] = v0;
            out[obase + 16] = v1;
            out[obase + 32] = v2;
            out[obase + 48] = v3;
        }
    }
}

extern "C" void kernel_launch(void* const* d_in, const int* in_sizes, int n_in,
                              void* d_out, int out_size, void* d_ws, size_t ws_size,
                              hipStream_t stream) {
    const float* X   = (const float*)d_in[0];   // (B, N, FIN) fp32
    const int*   adj = (const int*)  d_in[1];   // (B, N, N) int32
    const float* W   = (const float*)d_in[2];   // (FIN, FOUT) fp32
    const float* a   = (const float*)d_in[3];   // (2*FOUT, 1) fp32
    float* out = (float*)d_out;                 // (B, N, FOUT) fp32

    float* ws = (float*)d_ws;
    float* ht = ws;                             // B*FOUT*N_ = 4194304 floats
    float* s  = ht + (size_t)B_ * FOUT * N_;    // 65536
    float* t  = s + B_ * N_;                    // 65536
    float* Wt = t + B_ * N_;                    // 8192

    k_wt<<<1, 256, 0, stream>>>(W, Wt);
    k_h<<<(B_ * N_) / 256, 256, 0, stream>>>(X, Wt, a, ht, s, t);
    k_attn<<<B_ * 2, 256, 0, stream>>>(adj, ht, s, t, out);
}

// Round 2
// 232.275 us; speedup vs baseline: 1.3871x; 1.3871x over previous
//
#include <hip/hip_runtime.h>
#include <stdint.h>

#define B_   128
#define N_   512
#define FIN  128
#define FOUT 64

using bf16x8 = __attribute__((ext_vector_type(8))) short;
using f32x4  = __attribute__((ext_vector_type(4))) float;

__device__ inline unsigned short f2bf(float x) {
    union { float f; uint32_t u; } c; c.f = x;
    uint32_t u = c.u;
    return (unsigned short)((u + 0x7FFFu + ((u >> 16) & 1u)) >> 16);  // RNE
}

// ---------------- kernel 1: h = X @ W via bf16 MFMA ----------------
// grid 512 = (b<<2)|quarter, 256 threads (4 waves), 2 blocks/CU.
// Writes ht transposed+bf16: htT[b][f][j], plus s,t (fp32).
__global__ __launch_bounds__(256) void k_h(const float* __restrict__ X,
                                           const float* __restrict__ W,
                                           const float* __restrict__ a,
                                           uint16_t* __restrict__ htT,
                                           float* __restrict__ s,
                                           float* __restrict__ t) {
    __shared__ bf16x8 ax[32 * 64];   // A fragments: 8 rt x 4 ks, 32 KB
    __shared__ bf16x8 wl[16 * 64];   // W fragments: 4 ks x 4 nt, 16 KB

    const int b  = blockIdx.x >> 2;
    const int j0 = (blockIdx.x & 3) * 128;
    const int tid = threadIdx.x;
    const int w = tid >> 6, lane = tid & 63;
    const int q = lane >> 4, m = lane & 15;

    // ---- stage W fragments (ks = w): B[k][n], k=q*8+u, n=m ----
#pragma unroll
    for (int nt = 0; nt < 4; ++nt) {
        bf16x8 fr;
#pragma unroll
        for (int u = 0; u < 8; ++u)
            fr[u] = (short)f2bf(W[(w * 32 + q * 8 + u) * FOUT + nt * 16 + m]);
        wl[(w * 4 + nt) * 64 + lane] = fr;
    }

    // ---- stage X fragments: A[m][k], k=q*8+u ----
    const float* xb = X + ((size_t)(b * N_) + j0) * FIN;
#pragma unroll
    for (int i = 0; i < 8; ++i) {
        int pi = i * 4 + w, rt = pi >> 2, ks = pi & 3;
        const float* src = xb + (size_t)(rt * 16 + m) * FIN + ks * 32 + q * 8;
        float4 v0 = *(const float4*)src;
        float4 v1 = *(const float4*)(src + 4);
        bf16x8 fr;
        fr[0] = (short)f2bf(v0.x); fr[1] = (short)f2bf(v0.y);
        fr[2] = (short)f2bf(v0.z); fr[3] = (short)f2bf(v0.w);
        fr[4] = (short)f2bf(v1.x); fr[5] = (short)f2bf(v1.y);
        fr[6] = (short)f2bf(v1.z); fr[7] = (short)f2bf(v1.w);
        ax[pi * 64 + lane] = fr;
    }
    __syncthreads();

    float asv[4], adv[4];
#pragma unroll
    for (int nt = 0; nt < 4; ++nt) {
        asv[nt] = a[nt * 16 + m];
        adv[nt] = a[FOUT + nt * 16 + m];
    }

    for (int rl = 0; rl < 2; ++rl) {
        const int rt = w + rl * 4;
        f32x4 acc[4] = {{0.f,0.f,0.f,0.f},{0.f,0.f,0.f,0.f},
                        {0.f,0.f,0.f,0.f},{0.f,0.f,0.f,0.f}};
#pragma unroll
        for (int ks = 0; ks < 4; ++ks) {
            bf16x8 af = ax[(rt * 4 + ks) * 64 + lane];
#pragma unroll
            for (int nt = 0; nt < 4; ++nt)
                acc[nt] = __builtin_amdgcn_mfma_f32_16x16x32_bf16(
                    af, wl[(ks * 4 + nt) * 64 + lane], acc[nt], 0, 0, 0);
        }

        // ---- s,t: per C-row dot with a_src/a_dst, reduce over m lanes ----
        float ps[4], pt[4];
#pragma unroll
        for (int r = 0; r < 4; ++r) {
            float vs = 0.f, vt = 0.f;
#pragma unroll
            for (int nt = 0; nt < 4; ++nt) {
                vs += acc[nt][r] * asv[nt];
                vt += acc[nt][r] * adv[nt];
            }
            vs += __shfl_xor(vs, 1, 64); vs += __shfl_xor(vs, 2, 64);
            vs += __shfl_xor(vs, 4, 64); vs += __shfl_xor(vs, 8, 64);
            vt += __shfl_xor(vt, 1, 64); vt += __shfl_xor(vt, 2, 64);
            vt += __shfl_xor(vt, 4, 64); vt += __shfl_xor(vt, 8, 64);
            ps[r] = vs; pt[r] = vt;
        }
        if (m < 4) {
            float vs = (m == 0) ? ps[0] : (m == 1) ? ps[1] : (m == 2) ? ps[2] : ps[3];
            float vt = (m == 0) ? pt[0] : (m == 1) ? pt[1] : (m == 2) ? pt[2] : pt[3];
            int row = j0 + rt * 16 + q * 4 + m;
            s[b * N_ + row] = vs;
            t[b * N_ + row] = vt;
        }

        // ---- store htT[b][f][j] bf16: C row=q*4+reg -> j, col=m -> f ----
#pragma unroll
        for (int nt = 0; nt < 4; ++nt) {
            uint32_t d0 = (uint32_t)f2bf(acc[nt][0]) | ((uint32_t)f2bf(acc[nt][1]) << 16);
            uint32_t d1 = (uint32_t)f2bf(acc[nt][2]) | ((uint32_t)f2bf(acc[nt][3]) << 16);
            uint2 dd; dd.x = d0; dd.y = d1;
            *(uint2*)(htT + (size_t)(b * FOUT + nt * 16 + m) * N_ + j0 + rt * 16 + q * 4) = dd;
        }
    }
}

// ---------------- kernel 2: attention + aggregation (bf16 MFMA) ----------------
// grid 512 = (b<<2)|quarter (128 attention rows each), 256 threads, 2 blocks/CU.
// hstage loaded as a pure bf16 copy (k_h already transposed).
__global__ __launch_bounds__(256) void k_attn(const int*    __restrict__ adj,
                                              const uint16_t* __restrict__ htT,
                                              const float*  __restrict__ s,
                                              const float*  __restrict__ t,
                                              float*        __restrict__ out) {
    __shared__ bf16x8 hstage[64 * 64];   // 64 KB, [pi=ks*4+nt][lane]

    const int b  = blockIdx.x >> 2;
    const int i0 = (blockIdx.x & 3) * 128;
    const int tid = threadIdx.x;
    const int w = tid >> 6, lane = tid & 63;
    const int q = lane >> 4, m = lane & 15;

    // ---- stage H[b] fragments: B[k=j][n=f], straight bf16 copy ----
    const uint16_t* hb = htT + (size_t)b * FOUT * N_;
#pragma unroll
    for (int i = 0; i < 16; ++i) {
        int pi = i * 4 + w, ks = pi >> 2, nt = pi & 3;
        bf16x8 v = *(const bf16x8*)(hb + (size_t)(nt * 16 + m) * N_ + ks * 32 + q * 8);
        hstage[pi * 64 + lane] = v;
    }
    __syncthreads();

    const float* tb = t + b * N_;

    for (int rl = 0; rl < 2; ++rl) {
        const int rt = w + rl * 4;
        const int irow = i0 + rt * 16 + m;
        const float s_i = s[b * N_ + irow];
        const int* adjrow = adj + ((size_t)(b * N_) + irow) * N_;

        f32x4 acc0 = {0.f,0.f,0.f,0.f}, acc1 = {0.f,0.f,0.f,0.f};
        f32x4 acc2 = {0.f,0.f,0.f,0.f}, acc3 = {0.f,0.f,0.f,0.f};
        float lsum = 0.f;

        for (int ks = 0; ks < 16; ++ks) {
            const int jb = ks * 32 + q * 8;
            float4 t0 = *(const float4*)(tb + jb);
            float4 t1 = *(const float4*)(tb + jb + 4);
            int4  a0 = *(const int4*)(adjrow + jb);
            int4  a1 = *(const int4*)(adjrow + jb + 4);

            float tj[8] = {t0.x, t0.y, t0.z, t0.w, t1.x, t1.y, t1.z, t1.w};
            int   av[8] = {a0.x, a0.y, a0.z, a0.w, a1.x, a1.y, a1.z, a1.w};
            float pv[8];
#pragma unroll
            for (int u = 0; u < 8; ++u) {
                float e = s_i + tj[u];
                e = fmaxf(e, 0.2f * e);             // leaky_relu(e, 0.2)
                pv[u] = (av[u] > 0) ? __expf(e) : 0.0f;
                lsum += pv[u];
            }
            bf16x8 af;
#pragma unroll
            for (int u = 0; u < 8; ++u) af[u] = (short)f2bf(pv[u]);

            bf16x8 b0 = hstage[(ks * 4 + 0) * 64 + lane];
            bf16x8 b1 = hstage[(ks * 4 + 1) * 64 + lane];
            bf16x8 b2 = hstage[(ks * 4 + 2) * 64 + lane];
            bf16x8 b3 = hstage[(ks * 4 + 3) * 64 + lane];

            acc0 = __builtin_amdgcn_mfma_f32_16x16x32_bf16(af, b0, acc0, 0, 0, 0);
            acc1 = __builtin_amdgcn_mfma_f32_16x16x32_bf16(af, b1, acc1, 0, 0, 0);
            acc2 = __builtin_amdgcn_mfma_f32_16x16x32_bf16(af, b2, acc2, 0, 0, 0);
            acc3 = __builtin_amdgcn_mfma_f32_16x16x32_bf16(af, b3, acc3, 0, 0, 0);
        }

        // row-sum l over q groups (lanes differ in bits 4,5)
        lsum += __shfl_xor(lsum, 16, 64);
        lsum += __shfl_xor(lsum, 32, 64);

#pragma unroll
        for (int reg = 0; reg < 4; ++reg) {
            float lr = __shfl(lsum, q * 4 + reg, 64);   // l for C-row q*4+reg (same m-col set)
            float inv = 1.0f / lr;
            int orow = i0 + rt * 16 + q * 4 + reg;
            size_t obase = ((size_t)(b * N_) + orow) * FOUT + m;
            float v0 = acc0[reg] * inv; v0 = fmaxf(v0, 0.01f * v0);
            float v1 = acc1[reg] * inv; v1 = fmaxf(v1, 0.01f * v1);
            float v2 = acc2[reg] * inv; v2 = fmaxf(v2, 0.01f * v2);
            float v3 = acc3[reg] * inv; v3 = fmaxf(v3, 0.01f * v3);
            out[obase +  0] = v0;
            out[obase + 16] = v1;
            out[obase + 32] = v2;
            out[obase + 48] = v3;
        }
    }
}

extern "C" void kernel_launch(void* const* d_in, const int* in_sizes, int n_in,
                              void* d_out, int out_size, void* d_ws, size_t ws_size,
                              hipStream_t stream) {
    const float* X   = (const float*)d_in[0];   // (B, N, FIN) fp32
    const int*   adj = (const int*)  d_in[1];   // (B, N, N) int32
    const float* W   = (const float*)d_in[2];   // (FIN, FOUT) fp32
    const float* a   = (const float*)d_in[3];   // (2*FOUT, 1) fp32
    float* out = (float*)d_out;                 // (B, N, FOUT) fp32

    uint16_t* htT = (uint16_t*)d_ws;                       // B*FOUT*N bf16 = 8 MB
    float* s = (float*)(htT + (size_t)B_ * FOUT * N_);     // 65536 floats
    float* t = s + B_ * N_;                                // 65536 floats

    k_h<<<B_ * 4, 256, 0, stream>>>(X, W, a, htT, s, t);
    k_attn<<<B_ * 4, 256, 0, stream>>>(adj, htT, s, t, out);
}

// Round 3
// 231.693 us; speedup vs baseline: 1.3906x; 1.0025x over previous
//
#include <hip/hip_runtime.h>
#include <stdint.h>

#define B_   128
#define N_   512
#define FIN  128
#define FOUT 64

using bf16x8 = __attribute__((ext_vector_type(8))) short;
using f32x4  = __attribute__((ext_vector_type(4))) float;

__device__ inline unsigned short f2bf(float x) {
    union { float f; uint32_t u; } c; c.f = x;
    uint32_t u = c.u;
    return (unsigned short)((u + 0x7FFFu + ((u >> 16) & 1u)) >> 16);  // RNE
}

// ---------------- kernel 1: h = X @ W via bf16 MFMA ----------------
// grid 512 = (b<<2)|quarter, 256 threads (4 waves), 3 blocks/CU (48 KB LDS).
// Writes ht transposed+bf16: htT[b][f][j], plus s,t (fp32).
__global__ __launch_bounds__(256) void k_h(const float* __restrict__ X,
                                           const float* __restrict__ W,
                                           const float* __restrict__ a,
                                           uint16_t* __restrict__ htT,
                                           float* __restrict__ s,
                                           float* __restrict__ t) {
    __shared__ bf16x8 ax[32 * 64];   // A fragments: 8 rt x 4 ks, 32 KB
    __shared__ bf16x8 wl[16 * 64];   // W fragments: 4 ks x 4 nt, 16 KB

    const int b  = blockIdx.x >> 2;
    const int j0 = (blockIdx.x & 3) * 128;
    const int tid = threadIdx.x;
    const int w = tid >> 6, lane = tid & 63;
    const int q = lane >> 4, m = lane & 15;

    // ---- stage W fragments (ks = w): B[k][n], k=q*8+u, n=m ----
#pragma unroll
    for (int nt = 0; nt < 4; ++nt) {
        bf16x8 fr;
#pragma unroll
        for (int u = 0; u < 8; ++u)
            fr[u] = (short)f2bf(W[(w * 32 + q * 8 + u) * FOUT + nt * 16 + m]);
        wl[(w * 4 + nt) * 64 + lane] = fr;
    }

    // ---- stage X fragments: A[m][k], k=q*8+u ----
    const float* xb = X + ((size_t)(b * N_) + j0) * FIN;
#pragma unroll
    for (int i = 0; i < 8; ++i) {
        int pi = i * 4 + w, rt = pi >> 2, ks = pi & 3;
        const float* src = xb + (size_t)(rt * 16 + m) * FIN + ks * 32 + q * 8;
        float4 v0 = *(const float4*)src;
        float4 v1 = *(const float4*)(src + 4);
        bf16x8 fr;
        fr[0] = (short)f2bf(v0.x); fr[1] = (short)f2bf(v0.y);
        fr[2] = (short)f2bf(v0.z); fr[3] = (short)f2bf(v0.w);
        fr[4] = (short)f2bf(v1.x); fr[5] = (short)f2bf(v1.y);
        fr[6] = (short)f2bf(v1.z); fr[7] = (short)f2bf(v1.w);
        ax[pi * 64 + lane] = fr;
    }
    __syncthreads();

    float asv[4], adv[4];
#pragma unroll
    for (int nt = 0; nt < 4; ++nt) {
        asv[nt] = a[nt * 16 + m];
        adv[nt] = a[FOUT + nt * 16 + m];
    }

    for (int rl = 0; rl < 2; ++rl) {
        const int rt = w + rl * 4;
        f32x4 acc[4] = {{0.f,0.f,0.f,0.f},{0.f,0.f,0.f,0.f},
                        {0.f,0.f,0.f,0.f},{0.f,0.f,0.f,0.f}};
#pragma unroll
        for (int ks = 0; ks < 4; ++ks) {
            bf16x8 af = ax[(rt * 4 + ks) * 64 + lane];
#pragma unroll
            for (int nt = 0; nt < 4; ++nt)
                acc[nt] = __builtin_amdgcn_mfma_f32_16x16x32_bf16(
                    af, wl[(ks * 4 + nt) * 64 + lane], acc[nt], 0, 0, 0);
        }

        // ---- s,t: per C-row dot with a_src/a_dst, reduce over m lanes ----
        float ps[4], pt[4];
#pragma unroll
        for (int r = 0; r < 4; ++r) {
            float vs = 0.f, vt = 0.f;
#pragma unroll
            for (int nt = 0; nt < 4; ++nt) {
                vs += acc[nt][r] * asv[nt];
                vt += acc[nt][r] * adv[nt];
            }
            vs += __shfl_xor(vs, 1, 64); vs += __shfl_xor(vs, 2, 64);
            vs += __shfl_xor(vs, 4, 64); vs += __shfl_xor(vs, 8, 64);
            vt += __shfl_xor(vt, 1, 64); vt += __shfl_xor(vt, 2, 64);
            vt += __shfl_xor(vt, 4, 64); vt += __shfl_xor(vt, 8, 64);
            ps[r] = vs; pt[r] = vt;
        }
        if (m < 4) {
            float vs = (m == 0) ? ps[0] : (m == 1) ? ps[1] : (m == 2) ? ps[2] : ps[3];
            float vt = (m == 0) ? pt[0] : (m == 1) ? pt[1] : (m == 2) ? pt[2] : pt[3];
            int row = j0 + rt * 16 + q * 4 + m;
            s[b * N_ + row] = vs;
            t[b * N_ + row] = vt;
        }

        // ---- store htT[b][f][j] bf16: C row=q*4+reg -> j, col=m -> f ----
#pragma unroll
        for (int nt = 0; nt < 4; ++nt) {
            uint32_t d0 = (uint32_t)f2bf(acc[nt][0]) | ((uint32_t)f2bf(acc[nt][1]) << 16);
            uint32_t d1 = (uint32_t)f2bf(acc[nt][2]) | ((uint32_t)f2bf(acc[nt][3]) << 16);
            uint2 dd; dd.x = d0; dd.y = d1;
            *(uint2*)(htT + (size_t)(b * FOUT + nt * 16 + m) * N_ + j0 + rt * 16 + q * 4) = dd;
        }
    }
}

// ---------------- kernel 2: attention + aggregation (bf16 MFMA) ----------------
// grid 512 = (b<<2)|quarter (128 rows), 256 threads, 2 blocks/CU (66 KB LDS).
// Both row-tiles fused in one K-loop (shared b-frags), adj prefetched 1 ks
// ahead, t staged in LDS. Softmax without max-subtraction; normalize in epilogue.
__global__ __launch_bounds__(256) void k_attn(const int*    __restrict__ adj,
                                              const uint16_t* __restrict__ htT,
                                              const float*  __restrict__ s,
                                              const float*  __restrict__ t,
                                              float*        __restrict__ out) {
    __shared__ bf16x8 hstage[64 * 64];   // 64 KB, [pi=ks*4+nt][lane]
    __shared__ float  tsh[N_];           // 2 KB

    const int b  = blockIdx.x >> 2;
    const int i0 = (blockIdx.x & 3) * 128;
    const int tid = threadIdx.x;
    const int w = tid >> 6, lane = tid & 63;
    const int q = lane >> 4, m = lane & 15;

    // ---- stage H[b] fragments (pure bf16 copy) + t ----
    const uint16_t* hb = htT + (size_t)b * FOUT * N_;
#pragma unroll
    for (int i = 0; i < 16; ++i) {
        int pi = i * 4 + w, ks = pi >> 2, nt = pi & 3;
        bf16x8 v = *(const bf16x8*)(hb + (size_t)(nt * 16 + m) * N_ + ks * 32 + q * 8);
        hstage[pi * 64 + lane] = v;
    }
    *(float2*)&tsh[tid * 2] = *(const float2*)(t + b * N_ + tid * 2);
    __syncthreads();

    const int ir0 = i0 + w * 16 + m;          // rt0 = w
    const int ir1 = ir0 + 64;                 // rt1 = w + 4
    const float s0 = s[b * N_ + ir0];
    const float s1 = s[b * N_ + ir1];
    const int* ar0 = adj + ((size_t)(b * N_) + ir0) * N_;
    const int* ar1 = adj + ((size_t)(b * N_) + ir1) * N_;

    f32x4 acc0[4] = {{0.f,0.f,0.f,0.f},{0.f,0.f,0.f,0.f},
                     {0.f,0.f,0.f,0.f},{0.f,0.f,0.f,0.f}};
    f32x4 acc1[4] = {{0.f,0.f,0.f,0.f},{0.f,0.f,0.f,0.f},
                     {0.f,0.f,0.f,0.f},{0.f,0.f,0.f,0.f}};
    float ls0 = 0.f, ls1 = 0.f;

    // prefetch ks = 0
    int4 c00 = *(const int4*)(ar0 + q * 8);
    int4 c01 = *(const int4*)(ar0 + q * 8 + 4);
    int4 c10 = *(const int4*)(ar1 + q * 8);
    int4 c11 = *(const int4*)(ar1 + q * 8 + 4);

    for (int ks = 0; ks < 16; ++ks) {
        // issue next-ks adj loads before any compute (clamped, branch-free)
        const int jn = ((ks < 15) ? ks + 1 : ks) * 32 + q * 8;
        int4 n00 = *(const int4*)(ar0 + jn);
        int4 n01 = *(const int4*)(ar0 + jn + 4);
        int4 n10 = *(const int4*)(ar1 + jn);
        int4 n11 = *(const int4*)(ar1 + jn + 4);

        const int jb = ks * 32 + q * 8;
        float tj[8];
#pragma unroll
        for (int u = 0; u < 8; ++u) tj[u] = tsh[jb + u];

        int av0[8] = {c00.x, c00.y, c00.z, c00.w, c01.x, c01.y, c01.z, c01.w};
        int av1[8] = {c10.x, c10.y, c10.z, c10.w, c11.x, c11.y, c11.z, c11.w};
        bf16x8 af0, af1;
#pragma unroll
        for (int u = 0; u < 8; ++u) {
            float e0 = s0 + tj[u];
            e0 = fmaxf(e0, 0.2f * e0);
            float p0 = (av0[u] > 0) ? __expf(e0) : 0.0f;
            ls0 += p0;
            af0[u] = (short)f2bf(p0);
            float e1 = s1 + tj[u];
            e1 = fmaxf(e1, 0.2f * e1);
            float p1 = (av1[u] > 0) ? __expf(e1) : 0.0f;
            ls1 += p1;
            af1[u] = (short)f2bf(p1);
        }

        bf16x8 bf0 = hstage[(ks * 4 + 0) * 64 + lane];
        bf16x8 bf1 = hstage[(ks * 4 + 1) * 64 + lane];
        bf16x8 bf2 = hstage[(ks * 4 + 2) * 64 + lane];
        bf16x8 bf3 = hstage[(ks * 4 + 3) * 64 + lane];

        acc0[0] = __builtin_amdgcn_mfma_f32_16x16x32_bf16(af0, bf0, acc0[0], 0, 0, 0);
        acc0[1] = __builtin_amdgcn_mfma_f32_16x16x32_bf16(af0, bf1, acc0[1], 0, 0, 0);
        acc0[2] = __builtin_amdgcn_mfma_f32_16x16x32_bf16(af0, bf2, acc0[2], 0, 0, 0);
        acc0[3] = __builtin_amdgcn_mfma_f32_16x16x32_bf16(af0, bf3, acc0[3], 0, 0, 0);
        acc1[0] = __builtin_amdgcn_mfma_f32_16x16x32_bf16(af1, bf0, acc1[0], 0, 0, 0);
        acc1[1] = __builtin_amdgcn_mfma_f32_16x16x32_bf16(af1, bf1, acc1[1], 0, 0, 0);
        acc1[2] = __builtin_amdgcn_mfma_f32_16x16x32_bf16(af1, bf2, acc1[2], 0, 0, 0);
        acc1[3] = __builtin_amdgcn_mfma_f32_16x16x32_bf16(af1, bf3, acc1[3], 0, 0, 0);

        c00 = n00; c01 = n01; c10 = n10; c11 = n11;
    }

    // row-sum l over q groups (lanes differ in bits 4,5)
    ls0 += __shfl_xor(ls0, 16, 64);
    ls0 += __shfl_xor(ls0, 32, 64);
    ls1 += __shfl_xor(ls1, 16, 64);
    ls1 += __shfl_xor(ls1, 32, 64);

#pragma unroll
    for (int reg = 0; reg < 4; ++reg) {
        float lr0 = __shfl(ls0, q * 4 + reg, 64);
        float lr1 = __shfl(ls1, q * 4 + reg, 64);
        float inv0 = 1.0f / lr0, inv1 = 1.0f / lr1;
        int orow0 = i0 + w * 16 + q * 4 + reg;
        size_t ob0 = ((size_t)(b * N_) + orow0) * FOUT + m;
        size_t ob1 = ob0 + (size_t)64 * FOUT;
#pragma unroll
        for (int nt = 0; nt < 4; ++nt) {
            float v0 = acc0[nt][reg] * inv0; v0 = fmaxf(v0, 0.01f * v0);
            float v1 = acc1[nt][reg] * inv1; v1 = fmaxf(v1, 0.01f * v1);
            out[ob0 + nt * 16] = v0;
            out[ob1 + nt * 16] = v1;
        }
    }
}

extern "C" void kernel_launch(void* const* d_in, const int* in_sizes, int n_in,
                              void* d_out, int out_size, void* d_ws, size_t ws_size,
                              hipStream_t stream) {
    const float* X   = (const float*)d_in[0];   // (B, N, FIN) fp32
    const int*   adj = (const int*)  d_in[1];   // (B, N, N) int32
    const float* W   = (const float*)d_in[2];   // (FIN, FOUT) fp32
    const float* a   = (const float*)d_in[3];   // (2*FOUT, 1) fp32
    float* out = (float*)d_out;                 // (B, N, FOUT) fp32

    uint16_t* htT = (uint16_t*)d_ws;                       // B*FOUT*N bf16 = 8 MB
    float* s = (float*)(htT + (size_t)B_ * FOUT * N_);     // 65536 floats
    float* t = s + B_ * N_;                                // 65536 floats

    k_h<<<B_ * 4, 256, 0, stream>>>(X, W, a, htT, s, t);
    k_attn<<<B_ * 4, 256, 0, stream>>>(adj, htT, s, t, out);
}